// Round 11
// baseline (2828.788 us; speedup 1.0000x reference)
//
#include <hip/hip_runtime.h>
#include <hip/hip_cooperative_groups.h>
#include <hip/hip_fp16.h>
#include <stdint.h>

#define NEG_SLOPE 0.2f
typedef _Float16 half_t;
typedef float  f32x4 __attribute__((ext_vector_type(4)));
typedef int    i32x4 __attribute__((ext_vector_type(4)));
namespace cg = cooperative_groups;

// One cooperative kernel: CSR build + 8 x (gemm phase, aggregate phase).
// Grid-stride everywhere; grid capped to co-resident occupancy at launch.
__global__ __launch_bounds__(256, 4)
void mega(const float* __restrict__ x0,
          const int* __restrict__ esrc, const int* __restrict__ edst,
          const float* __restrict__ Ws, const float* __restrict__ asrc,
          const float* __restrict__ adst, const float* __restrict__ biases,
          float* __restrict__ dout,
          half_t* __restrict__ h, float* __restrict__ bufA, float* __restrict__ bufB,
          float* __restrict__ s_src, float* __restrict__ s_dst,
          int* __restrict__ counts, int* __restrict__ offsets,
          int* __restrict__ cursor, int* __restrict__ ssorted,
          int N, int E, int L)
{
  cg::grid_group grid = cg::this_grid();
  __shared__ float xlds[16 * 64];
  __shared__ int   slds[256];

  const int tid  = threadIdx.x;
  const int bid  = blockIdx.x;
  const int G    = gridDim.x;
  const int gtid = bid * 256 + tid;
  const long NT  = (long)G * 256;

  // ---------------- CSR: zero counts ----------------
  for (int i = gtid; i < N; i += (int)NT) counts[i] = 0;
  grid.sync();

  // ---------------- CSR: histogram (4 edges/thread) ----------------
  for (long i0 = (long)gtid * 4; i0 < E; i0 += NT * 4){
    if (i0 + 3 < E){
      i32x4 d = __builtin_nontemporal_load((const i32x4*)(edst + i0));
      atomicAdd(counts + d.x, 1);
      atomicAdd(counts + d.y, 1);
      atomicAdd(counts + d.z, 1);
      atomicAdd(counts + d.w, 1);
    } else {
      for (long i = i0; i < E; ++i) atomicAdd(counts + edst[i], 1);
    }
  }
  grid.sync();

  // ---------------- CSR: exclusive scan (block 0 only) ----------------
  if (bid == 0){
    const int chunk = (N + 255) >> 8;
    const int beg = tid * chunk;
    const int end = min(beg + chunk, N);
    int s = 0;
    for (int i = beg; i < end; ++i) s += counts[i];
    slds[tid] = s;
    __syncthreads();
    for (int off = 1; off < 256; off <<= 1){
      int t = 0;
      if (tid >= off) t = slds[tid - off];
      __syncthreads();
      if (tid >= off) slds[tid] += t;
      __syncthreads();
    }
    int run = slds[tid] - s;
    for (int i = beg; i < end; ++i){
      offsets[i] = run;
      cursor[i]  = run;
      run += counts[i];
    }
    if (tid == 255) offsets[N] = slds[255];
  }
  grid.sync();

  // ---------------- CSR: scatter (4 edges/thread) ----------------
  for (long i0 = (long)gtid * 4; i0 < E; i0 += NT * 4){
    if (i0 + 3 < E){
      i32x4 sv = __builtin_nontemporal_load((const i32x4*)(esrc + i0));
      i32x4 dv = __builtin_nontemporal_load((const i32x4*)(edst + i0));
      int p0 = atomicAdd(cursor + dv.x, 1);
      int p1 = atomicAdd(cursor + dv.y, 1);
      int p2 = atomicAdd(cursor + dv.z, 1);
      int p3 = atomicAdd(cursor + dv.w, 1);
      if (p0 >= 0 && p0 < E) ssorted[p0] = sv.x;   // clamps: replay safety
      if (p1 >= 0 && p1 < E) ssorted[p1] = sv.y;
      if (p2 >= 0 && p2 < E) ssorted[p2] = sv.z;
      if (p3 >= 0 && p3 < E) ssorted[p3] = sv.w;
    } else {
      for (long i = i0; i < E; ++i){
        int d = edst[i];
        int pos = atomicAdd(cursor + d, 1);
        if (pos >= 0 && pos < E) ssorted[pos] = esrc[i];
      }
    }
  }
  grid.sync();

  // ---------------- layers ----------------
  const float* xin = x0;
  for (int l = 0; l < L; ++l){
    const float* W   = Ws     + (size_t)l * 4096;
    const float* as_ = asrc   + l * 64;
    const float* ad_ = adst   + l * 64;
    const float* b_  = biases + l * 64;
    float* xout = (l == L - 1) ? dout : ((l & 1) ? bufB : bufA);

    // ===== gemm phase: h = xin@W (fp16), fused score dots =====
    {
      const int lane = tid & 63;
      const int wave = tid >> 6;
      float wreg[64];
      #pragma unroll
      for (int k = 0; k < 64; ++k) wreg[k] = W[k * 64 + lane];
      const float asv = as_[lane];
      const float adv = ad_[lane];
      const int tiles = (N + 15) >> 4;
      for (int t = bid; t < tiles; t += G){
        __syncthreads();               // protect xlds reuse
        {
          int r = t * 16 + (tid >> 4);
          f32x4 v = {0.f, 0.f, 0.f, 0.f};
          if (r < N) v = __builtin_nontemporal_load(
              (const f32x4*)(xin + (size_t)r * 64 + (tid & 15) * 4));
          ((f32x4*)xlds)[tid] = v;
        }
        __syncthreads();
        for (int rr = wave; rr < 16; rr += 4){
          int row = t * 16 + rr;
          if (row >= N) break;         // uniform within wave
          const f32x4* xr = (const f32x4*)(xlds + rr * 64);
          float a0 = 0.0f, a1 = 0.0f;
          #pragma unroll
          for (int kk = 0; kk < 8; ++kk){
            f32x4 xv = xr[kk];
            a0 = fmaf(xv.x, wreg[4*kk+0], a0);
            a0 = fmaf(xv.y, wreg[4*kk+1], a0);
            a0 = fmaf(xv.z, wreg[4*kk+2], a0);
            a0 = fmaf(xv.w, wreg[4*kk+3], a0);
          }
          #pragma unroll
          for (int kk = 8; kk < 16; ++kk){
            f32x4 xv = xr[kk];
            a1 = fmaf(xv.x, wreg[4*kk+0], a1);
            a1 = fmaf(xv.y, wreg[4*kk+1], a1);
            a1 = fmaf(xv.z, wreg[4*kk+2], a1);
            a1 = fmaf(xv.w, wreg[4*kk+3], a1);
          }
          float acc = a0 + a1;
          h[(size_t)row * 64 + lane] = (half_t)acc;
          float ps = acc * asv;
          float pd = acc * adv;
          #pragma unroll
          for (int off = 1; off < 8; off <<= 1){
            ps += __shfl_xor(ps, off, 64);
            pd += __shfl_xor(pd, off, 64);
          }
          if ((lane & 7) == 0){
            s_src[row * 8 + (lane >> 3)] = ps;
            s_dst[row * 8 + (lane >> 3)] = pd;
          }
        }
      }
    }
    __threadfence();
    grid.sync();

    // ===== aggregate phase: segment softmax + weighted sum =====
    {
      const int lane = tid & 63;
      const int c8 = lane & 7;
      const int e8 = lane >> 3;
      const int gw = bid * 4 + (tid >> 6);
      const int NW = G * 4;
      union Cvt { float4 f4; half_t hx[8]; };

      for (int node = gw; node < N; node += NW){
        int beg = offsets[node];
        int end = offsets[node + 1];
        beg = max(0, min(beg, E));
        end = max(0, min(end, E));
        const int nv = end - beg + 1;            // +1 self-loop
        const float sdst = s_dst[node * 8 + c8];

        float m = -3.0e38f;
        float z = 0.0f;
        float acc[8];
        #pragma unroll
        for (int j = 0; j < 8; ++j) acc[j] = 0.0f;

        if (nv <= 64){
          const int cnt = (e8 < nv) ? ((nv - e8 + 7) >> 3) : 0;
          int sidx[8];
          #pragma unroll
          for (int j = 0; j < 8; ++j){
            int v = e8 + 8 * j;
            if (j < cnt)
              sidx[j] = (v == 0) ? node
                       : __builtin_nontemporal_load(ssorted + beg + v - 1);
          }
          float sc[8];
          #pragma unroll
          for (int j = 0; j < 8; ++j){
            if (j < cnt){
              float s = s_src[sidx[j] * 8 + c8] + sdst;
              sc[j] = (s > 0.0f) ? s : NEG_SLOPE * s;
            }
          }
          float4 hraw[8];
          #pragma unroll
          for (int j = 0; j < 8; ++j){
            if (j < cnt)
              hraw[j] = *(const float4*)(h + (size_t)sidx[j] * 64 + c8 * 8);
          }
          #pragma unroll
          for (int j = 0; j < 8; ++j)
            if (j < cnt) m = fmaxf(m, sc[j]);
          m = fmaxf(m, __shfl_xor(m, 8, 64));
          m = fmaxf(m, __shfl_xor(m, 16, 64));
          m = fmaxf(m, __shfl_xor(m, 32, 64));
          #pragma unroll
          for (int j = 0; j < 8; ++j){
            if (j < cnt){
              float e = __expf(sc[j] - m);
              z += e;
              Cvt u; u.f4 = hraw[j];
              #pragma unroll
              for (int k = 0; k < 8; ++k)
                acc[k] = fmaf(e, (float)u.hx[k], acc[k]);
            }
          }
        } else {
          for (int v = e8; v < nv; v += 8){
            int s = (v == 0) ? node : ssorted[beg + v - 1];
            float scv = s_src[s * 8 + c8] + sdst;
            scv = (scv > 0.0f) ? scv : NEG_SLOPE * scv;
            m = fmaxf(m, scv);
          }
          m = fmaxf(m, __shfl_xor(m, 8, 64));
          m = fmaxf(m, __shfl_xor(m, 16, 64));
          m = fmaxf(m, __shfl_xor(m, 32, 64));
          for (int v = e8; v < nv; v += 8){
            int s = (v == 0) ? node : ssorted[beg + v - 1];
            float scv = s_src[s * 8 + c8] + sdst;
            scv = (scv > 0.0f) ? scv : NEG_SLOPE * scv;
            float e = __expf(scv - m);
            z += e;
            Cvt u; u.f4 = *(const float4*)(h + (size_t)s * 64 + c8 * 8);
            #pragma unroll
            for (int k = 0; k < 8; ++k)
              acc[k] = fmaf(e, (float)u.hx[k], acc[k]);
          }
        }

        #pragma unroll
        for (int off = 8; off < 64; off <<= 1){
          z += __shfl_xor(z, off, 64);
          #pragma unroll
          for (int j = 0; j < 8; ++j) acc[j] += __shfl_xor(acc[j], off, 64);
        }

        if (e8 == 0){
          float inv = 1.0f / (z + 1e-16f);
          const float4* bp = (const float4*)(b_ + c8 * 8);
          float4 b0 = bp[0], b1 = bp[1];
          f32x4 o0, o1;
          o0.x = acc[0] * inv + b0.x;
          o0.y = acc[1] * inv + b0.y;
          o0.z = acc[2] * inv + b0.z;
          o0.w = acc[3] * inv + b0.w;
          o1.x = acc[4] * inv + b1.x;
          o1.y = acc[5] * inv + b1.y;
          o1.z = acc[6] * inv + b1.z;
          o1.w = acc[7] * inv + b1.w;
          f32x4* op = (f32x4*)(xout + (size_t)node * 64 + c8 * 8);
          __builtin_nontemporal_store(o0, op);
          __builtin_nontemporal_store(o1, op + 1);
        }
      }
    }
    __threadfence();
    grid.sync();
    xin = xout;
  }
}

// ---------------------------------------------------------------- launch
extern "C" void kernel_launch(void* const* d_in, const int* in_sizes, int n_in,
                              void* d_out, int out_size, void* d_ws, size_t ws_size,
                              hipStream_t stream){
  const float* x0   = (const float*)d_in[0];
  const int*   eidx = (const int*)  d_in[1];   // [2, E]
  const float* Ws   = (const float*)d_in[2];   // [L, 64, 64]
  const float* asrc = (const float*)d_in[3];   // [L, 8, 8]
  const float* adst = (const float*)d_in[4];   // [L, 8, 8]
  const float* bias = (const float*)d_in[5];   // [L, 64]

  const int N = in_sizes[0] / 64;
  const int E = in_sizes[1] / 2;
  const int L = in_sizes[2] / (64 * 64);

  char* ws = (char*)d_ws;
  size_t off = 0;
  auto alloc = [&](size_t bytes) -> void* {
    void* p = ws + off;
    off = (off + bytes + 255) & ~(size_t)255;
    return p;
  };
  half_t* hbuf   = (half_t*)alloc((size_t)N * 64 * sizeof(half_t));
  float* bufA    = (float*)alloc((size_t)N * 64 * sizeof(float));
  float* bufB    = (float*)alloc((size_t)N * 64 * sizeof(float));
  float* ssrc    = (float*)alloc((size_t)N * 8 * sizeof(float));
  float* sdstb   = (float*)alloc((size_t)N * 8 * sizeof(float));
  int*   counts  = (int*)alloc((size_t)N * sizeof(int));
  int*   offsets = (int*)alloc((size_t)(N + 1) * sizeof(int));
  int*   cursor  = (int*)alloc((size_t)N * sizeof(int));
  int*   ssorted = (int*)alloc((size_t)E * sizeof(int));

  const int* esrc = eidx;
  const int* edst = eidx + E;

  // co-residency-safe grid: query occupancy, cap at 1024 blocks (4/CU target)
  int occ = 0;
  hipOccupancyMaxActiveBlocksPerMultiprocessor(&occ, mega, 256, 0);
  if (occ < 1) occ = 1;
  int grid = occ * 256;               // 256 CUs on MI355X
  if (grid > 1024) grid = 1024;

  float* doutp = (float*)d_out;
  void* args[] = {
    (void*)&x0, (void*)&esrc, (void*)&edst, (void*)&Ws, (void*)&asrc,
    (void*)&adst, (void*)&bias, (void*)&doutp,
    (void*)&hbuf, (void*)&bufA, (void*)&bufB, (void*)&ssrc, (void*)&sdstb,
    (void*)&counts, (void*)&offsets, (void*)&cursor, (void*)&ssorted,
    (void*)&N, (void*)&E, (void*)&L
  };
  hipLaunchCooperativeKernel((const void*)mega, dim3(grid), dim3(256),
                             args, 0, stream);
}

// Round 12
// 1752.366 us; speedup vs baseline: 1.6143x; 1.6143x over previous
//
#include <hip/hip_runtime.h>
#include <hip/hip_cooperative_groups.h>
#include <hip/hip_fp16.h>
#include <stdint.h>

#define NEG_SLOPE 0.2f
typedef _Float16 half_t;
typedef float  f32x4 __attribute__((ext_vector_type(4)));
typedef int    i32x4 __attribute__((ext_vector_type(4)));
namespace cg = cooperative_groups;

// One cooperative kernel: CSR build + 8 x (gemm phase, aggregate phase).
// Grid-stride everywhere; grid capped to co-resident occupancy at launch.
// NOTE: no min-waves in launch_bounds -- R11's (256,4) capped VGPRs at 128,
// spilled wreg[64] to scratch (WRITE_SIZE 1.07GB, 6x slowdown).
__global__ __launch_bounds__(256)
void mega(const float* __restrict__ x0,
          const int* __restrict__ esrc, const int* __restrict__ edst,
          const float* __restrict__ Ws, const float* __restrict__ asrc,
          const float* __restrict__ adst, const float* __restrict__ biases,
          float* __restrict__ dout,
          half_t* __restrict__ h, float* __restrict__ bufA, float* __restrict__ bufB,
          float* __restrict__ s_src, float* __restrict__ s_dst,
          int* __restrict__ counts, int* __restrict__ offsets,
          int* __restrict__ cursor, int* __restrict__ ssorted,
          int N, int E, int L)
{
  cg::grid_group grid = cg::this_grid();
  __shared__ float xlds[16 * 64];
  __shared__ int   slds[256];

  const int tid  = threadIdx.x;
  const int bid  = blockIdx.x;
  const int G    = gridDim.x;
  const int gtid = bid * 256 + tid;
  const long NT  = (long)G * 256;

  // ---------------- CSR: zero counts ----------------
  for (int i = gtid; i < N; i += (int)NT) counts[i] = 0;
  grid.sync();

  // ---------------- CSR: histogram (4 edges/thread) ----------------
  for (long i0 = (long)gtid * 4; i0 < E; i0 += NT * 4){
    if (i0 + 3 < E){
      i32x4 d = __builtin_nontemporal_load((const i32x4*)(edst + i0));
      atomicAdd(counts + d.x, 1);
      atomicAdd(counts + d.y, 1);
      atomicAdd(counts + d.z, 1);
      atomicAdd(counts + d.w, 1);
    } else {
      for (long i = i0; i < E; ++i) atomicAdd(counts + edst[i], 1);
    }
  }
  grid.sync();

  // ---------------- CSR: exclusive scan (block 0 only) ----------------
  if (bid == 0){
    const int chunk = (N + 255) >> 8;
    const int beg = tid * chunk;
    const int end = min(beg + chunk, N);
    int s = 0;
    for (int i = beg; i < end; ++i) s += counts[i];
    slds[tid] = s;
    __syncthreads();
    for (int off = 1; off < 256; off <<= 1){
      int t = 0;
      if (tid >= off) t = slds[tid - off];
      __syncthreads();
      if (tid >= off) slds[tid] += t;
      __syncthreads();
    }
    int run = slds[tid] - s;
    for (int i = beg; i < end; ++i){
      offsets[i] = run;
      cursor[i]  = run;
      run += counts[i];
    }
    if (tid == 255) offsets[N] = slds[255];
  }
  grid.sync();

  // ---------------- CSR: scatter (4 edges/thread) ----------------
  for (long i0 = (long)gtid * 4; i0 < E; i0 += NT * 4){
    if (i0 + 3 < E){
      i32x4 sv = __builtin_nontemporal_load((const i32x4*)(esrc + i0));
      i32x4 dv = __builtin_nontemporal_load((const i32x4*)(edst + i0));
      int p0 = atomicAdd(cursor + dv.x, 1);
      int p1 = atomicAdd(cursor + dv.y, 1);
      int p2 = atomicAdd(cursor + dv.z, 1);
      int p3 = atomicAdd(cursor + dv.w, 1);
      if (p0 >= 0 && p0 < E) ssorted[p0] = sv.x;   // clamps: replay safety
      if (p1 >= 0 && p1 < E) ssorted[p1] = sv.y;
      if (p2 >= 0 && p2 < E) ssorted[p2] = sv.z;
      if (p3 >= 0 && p3 < E) ssorted[p3] = sv.w;
    } else {
      for (long i = i0; i < E; ++i){
        int d = edst[i];
        int pos = atomicAdd(cursor + d, 1);
        if (pos >= 0 && pos < E) ssorted[pos] = esrc[i];
      }
    }
  }
  grid.sync();

  // ---------------- layers ----------------
  const float* xin = x0;
  for (int l = 0; l < L; ++l){
    const float* W   = Ws     + (size_t)l * 4096;
    const float* as_ = asrc   + l * 64;
    const float* ad_ = adst   + l * 64;
    const float* b_  = biases + l * 64;
    float* xout = (l == L - 1) ? dout : ((l & 1) ? bufB : bufA);

    // ===== gemm phase: h = xin@W (fp16), fused score dots =====
    {
      const int lane = tid & 63;
      const int wave = tid >> 6;
      float wreg[64];
      #pragma unroll
      for (int k = 0; k < 64; ++k) wreg[k] = W[k * 64 + lane];
      const float asv = as_[lane];
      const float adv = ad_[lane];
      const int tiles = (N + 15) >> 4;
      for (int t = bid; t < tiles; t += G){
        __syncthreads();               // protect xlds reuse
        {
          int r = t * 16 + (tid >> 4);
          f32x4 v = {0.f, 0.f, 0.f, 0.f};
          if (r < N) v = __builtin_nontemporal_load(
              (const f32x4*)(xin + (size_t)r * 64 + (tid & 15) * 4));
          ((f32x4*)xlds)[tid] = v;
        }
        __syncthreads();
        for (int rr = wave; rr < 16; rr += 4){
          int row = t * 16 + rr;
          if (row >= N) break;         // uniform within wave
          const f32x4* xr = (const f32x4*)(xlds + rr * 64);
          float a0 = 0.0f, a1 = 0.0f;
          #pragma unroll
          for (int kk = 0; kk < 8; ++kk){
            f32x4 xv = xr[kk];
            a0 = fmaf(xv.x, wreg[4*kk+0], a0);
            a0 = fmaf(xv.y, wreg[4*kk+1], a0);
            a0 = fmaf(xv.z, wreg[4*kk+2], a0);
            a0 = fmaf(xv.w, wreg[4*kk+3], a0);
          }
          #pragma unroll
          for (int kk = 8; kk < 16; ++kk){
            f32x4 xv = xr[kk];
            a1 = fmaf(xv.x, wreg[4*kk+0], a1);
            a1 = fmaf(xv.y, wreg[4*kk+1], a1);
            a1 = fmaf(xv.z, wreg[4*kk+2], a1);
            a1 = fmaf(xv.w, wreg[4*kk+3], a1);
          }
          float acc = a0 + a1;
          h[(size_t)row * 64 + lane] = (half_t)acc;
          float ps = acc * asv;
          float pd = acc * adv;
          #pragma unroll
          for (int off = 1; off < 8; off <<= 1){
            ps += __shfl_xor(ps, off, 64);
            pd += __shfl_xor(pd, off, 64);
          }
          if ((lane & 7) == 0){
            s_src[row * 8 + (lane >> 3)] = ps;
            s_dst[row * 8 + (lane >> 3)] = pd;
          }
        }
      }
    }
    __threadfence();
    grid.sync();

    // ===== aggregate phase: segment softmax + weighted sum =====
    {
      const int lane = tid & 63;
      const int c8 = lane & 7;
      const int e8 = lane >> 3;
      const int gw = bid * 4 + (tid >> 6);
      const int NW = G * 4;
      union Cvt { float4 f4; half_t hx[8]; };

      for (int node = gw; node < N; node += NW){
        int beg = offsets[node];
        int end = offsets[node + 1];
        beg = max(0, min(beg, E));
        end = max(0, min(end, E));
        const int nv = end - beg + 1;            // +1 self-loop
        const float sdst = s_dst[node * 8 + c8];

        float m = -3.0e38f;
        float z = 0.0f;
        float acc[8];
        #pragma unroll
        for (int j = 0; j < 8; ++j) acc[j] = 0.0f;

        if (nv <= 64){
          const int cnt = (e8 < nv) ? ((nv - e8 + 7) >> 3) : 0;
          int sidx[8];
          #pragma unroll
          for (int j = 0; j < 8; ++j){
            int v = e8 + 8 * j;
            if (j < cnt)
              sidx[j] = (v == 0) ? node
                       : __builtin_nontemporal_load(ssorted + beg + v - 1);
          }
          float sc[8];
          #pragma unroll
          for (int j = 0; j < 8; ++j){
            if (j < cnt){
              float s = s_src[sidx[j] * 8 + c8] + sdst;
              sc[j] = (s > 0.0f) ? s : NEG_SLOPE * s;
            }
          }
          float4 hraw[8];
          #pragma unroll
          for (int j = 0; j < 8; ++j){
            if (j < cnt)
              hraw[j] = *(const float4*)(h + (size_t)sidx[j] * 64 + c8 * 8);
          }
          #pragma unroll
          for (int j = 0; j < 8; ++j)
            if (j < cnt) m = fmaxf(m, sc[j]);
          m = fmaxf(m, __shfl_xor(m, 8, 64));
          m = fmaxf(m, __shfl_xor(m, 16, 64));
          m = fmaxf(m, __shfl_xor(m, 32, 64));
          #pragma unroll
          for (int j = 0; j < 8; ++j){
            if (j < cnt){
              float e = __expf(sc[j] - m);
              z += e;
              Cvt u; u.f4 = hraw[j];
              #pragma unroll
              for (int k = 0; k < 8; ++k)
                acc[k] = fmaf(e, (float)u.hx[k], acc[k]);
            }
          }
        } else {
          for (int v = e8; v < nv; v += 8){
            int s = (v == 0) ? node : ssorted[beg + v - 1];
            float scv = s_src[s * 8 + c8] + sdst;
            scv = (scv > 0.0f) ? scv : NEG_SLOPE * scv;
            m = fmaxf(m, scv);
          }
          m = fmaxf(m, __shfl_xor(m, 8, 64));
          m = fmaxf(m, __shfl_xor(m, 16, 64));
          m = fmaxf(m, __shfl_xor(m, 32, 64));
          for (int v = e8; v < nv; v += 8){
            int s = (v == 0) ? node : ssorted[beg + v - 1];
            float scv = s_src[s * 8 + c8] + sdst;
            scv = (scv > 0.0f) ? scv : NEG_SLOPE * scv;
            float e = __expf(scv - m);
            z += e;
            Cvt u; u.f4 = *(const float4*)(h + (size_t)s * 64 + c8 * 8);
            #pragma unroll
            for (int k = 0; k < 8; ++k)
              acc[k] = fmaf(e, (float)u.hx[k], acc[k]);
          }
        }

        #pragma unroll
        for (int off = 8; off < 64; off <<= 1){
          z += __shfl_xor(z, off, 64);
          #pragma unroll
          for (int j = 0; j < 8; ++j) acc[j] += __shfl_xor(acc[j], off, 64);
        }

        if (e8 == 0){
          float inv = 1.0f / (z + 1e-16f);
          const float4* bp = (const float4*)(b_ + c8 * 8);
          float4 b0 = bp[0], b1 = bp[1];
          f32x4 o0, o1;
          o0.x = acc[0] * inv + b0.x;
          o0.y = acc[1] * inv + b0.y;
          o0.z = acc[2] * inv + b0.z;
          o0.w = acc[3] * inv + b0.w;
          o1.x = acc[4] * inv + b1.x;
          o1.y = acc[5] * inv + b1.y;
          o1.z = acc[6] * inv + b1.z;
          o1.w = acc[7] * inv + b1.w;
          f32x4* op = (f32x4*)(xout + (size_t)node * 64 + c8 * 8);
          __builtin_nontemporal_store(o0, op);
          __builtin_nontemporal_store(o1, op + 1);
        }
      }
    }
    __threadfence();
    grid.sync();
    xin = xout;
  }
}

// ---------------------------------------------------------------- launch
extern "C" void kernel_launch(void* const* d_in, const int* in_sizes, int n_in,
                              void* d_out, int out_size, void* d_ws, size_t ws_size,
                              hipStream_t stream){
  const float* x0   = (const float*)d_in[0];
  const int*   eidx = (const int*)  d_in[1];   // [2, E]
  const float* Ws   = (const float*)d_in[2];   // [L, 64, 64]
  const float* asrc = (const float*)d_in[3];   // [L, 8, 8]
  const float* adst = (const float*)d_in[4];   // [L, 8, 8]
  const float* bias = (const float*)d_in[5];   // [L, 64]

  const int N = in_sizes[0] / 64;
  const int E = in_sizes[1] / 2;
  const int L = in_sizes[2] / (64 * 64);

  char* ws = (char*)d_ws;
  size_t off = 0;
  auto alloc = [&](size_t bytes) -> void* {
    void* p = ws + off;
    off = (off + bytes + 255) & ~(size_t)255;
    return p;
  };
  half_t* hbuf   = (half_t*)alloc((size_t)N * 64 * sizeof(half_t));
  float* bufA    = (float*)alloc((size_t)N * 64 * sizeof(float));
  float* bufB    = (float*)alloc((size_t)N * 64 * sizeof(float));
  float* ssrc    = (float*)alloc((size_t)N * 8 * sizeof(float));
  float* sdstb   = (float*)alloc((size_t)N * 8 * sizeof(float));
  int*   counts  = (int*)alloc((size_t)N * sizeof(int));
  int*   offsets = (int*)alloc((size_t)(N + 1) * sizeof(int));
  int*   cursor  = (int*)alloc((size_t)N * sizeof(int));
  int*   ssorted = (int*)alloc((size_t)E * sizeof(int));

  const int* esrc = eidx;
  const int* edst = eidx + E;

  // co-residency-safe grid: query occupancy (true VGPR footprint), cap 1024
  int occ = 0;
  hipOccupancyMaxActiveBlocksPerMultiprocessor(&occ, mega, 256, 0);
  if (occ < 1) occ = 1;
  int grid = occ * 256;               // 256 CUs on MI355X
  if (grid > 1024) grid = 1024;

  float* doutp = (float*)d_out;
  void* args[] = {
    (void*)&x0, (void*)&esrc, (void*)&edst, (void*)&Ws, (void*)&asrc,
    (void*)&adst, (void*)&bias, (void*)&doutp,
    (void*)&hbuf, (void*)&bufA, (void*)&bufB, (void*)&ssrc, (void*)&sdstb,
    (void*)&counts, (void*)&offsets, (void*)&cursor, (void*)&ssorted,
    (void*)&N, (void*)&E, (void*)&L
  };
  hipLaunchCooperativeKernel((const void*)mega, dim3(grid), dim3(256),
                             args, 0, stream);
}